// Round 1
// baseline (341.109 us; speedup 1.0000x reference)
//
#include <hip/hip_runtime.h>
#include <hip/hip_bf16.h>

// Problem constants
#define BATCH 32
#define NNODE 4096
#define CIN 32
#define COUT 64
#define KDEG 5
#define POOL 4
#define NNZ_E 65536
#define BC (BATCH * CIN)        // 1024 floats per node-row
#define BC4 (BC / 4)            // 256 float4 per node-row
#define TFLOATS (NNODE * BC)    // 4,194,304 floats per Chebyshev level

// ---------------- CSR build ----------------

__global__ void hist_kernel(const int* __restrict__ erow, int* __restrict__ cnt) {
    int e = blockIdx.x * blockDim.x + threadIdx.x;
    if (e < NNZ_E) atomicAdd(&cnt[erow[e]], 1);
}

// 256 threads, each handles 16 counters. Produces row_start[0..NNODE] and cursor copy.
__global__ void scan_kernel(const int* __restrict__ cnt, int* __restrict__ row_start,
                            int* __restrict__ cursor) {
    __shared__ int sums[256];
    int tid = threadIdx.x;
    int local[16];
    int s = 0;
#pragma unroll
    for (int i = 0; i < 16; i++) { local[i] = cnt[tid * 16 + i]; s += local[i]; }
    sums[tid] = s;
    __syncthreads();
    // inclusive Hillis-Steele scan over 256 partials
    for (int off = 1; off < 256; off <<= 1) {
        int v = 0;
        if (tid >= off) v = sums[tid - off];
        __syncthreads();
        if (tid >= off) sums[tid] += v;
        __syncthreads();
    }
    int base = sums[tid] - s;   // exclusive prefix
    int run = base;
#pragma unroll
    for (int i = 0; i < 16; i++) {
        int r = tid * 16 + i;
        row_start[r] = run;
        cursor[r] = run;
        run += local[i];
    }
    if (tid == 255) row_start[NNODE] = sums[255];
}

__global__ void scatter_kernel(const int* __restrict__ erow, int* __restrict__ cursor,
                               int* __restrict__ perm) {
    int e = blockIdx.x * blockDim.x + threadIdx.x;
    if (e < NNZ_E) {
        int r = erow[e];
        int pos = atomicAdd(&cursor[r], 1);
        perm[pos] = e;
    }
}

// ---------------- transpose x [B][N][C] -> t0 [N][B*C] ----------------

__global__ void transpose_kernel(const float* __restrict__ x, float* __restrict__ t0) {
    // one float4 per thread over 1,048,576 float4 elements
    int idx = blockIdx.x * blockDim.x + threadIdx.x;   // [0, TFLOATS/4)
    int n  = idx >> 8;           // /256
    int rem = idx & 255;
    int b  = rem >> 3;           // /8
    int c4 = rem & 7;
    const float4* x4 = (const float4*)x;
    float4 v = x4[(b * NNODE + n) * 8 + c4];
    ((float4*)t0)[idx] = v;
}

// ---------------- fused Chebyshev SpMM: out = scale * (L @ in) - sub ----------------

__global__ void spmm_cheb_kernel(const float* __restrict__ in, const float* __restrict__ sub,
                                 float* __restrict__ out, float scale, int has_sub,
                                 const int* __restrict__ row_start, const int* __restrict__ perm,
                                 const float* __restrict__ eval, const int* __restrict__ ecol) {
    __shared__ float sval[256];
    __shared__ int   scol[256];
    int n = blockIdx.x;
    int tid = threadIdx.x;
    int beg = row_start[n], end = row_start[n + 1];

    float4 acc = make_float4(0.f, 0.f, 0.f, 0.f);
    const float4* in4 = (const float4*)in;

    for (int base = beg; base < end; base += 256) {
        int m = end - base; if (m > 256) m = 256;
        if (tid < m) {
            int e = perm[base + tid];
            sval[tid] = eval[e];
            scol[tid] = ecol[e];
        }
        __syncthreads();
#pragma unroll 4
        for (int i = 0; i < m; i++) {
            float v = sval[i];
            int c = scol[i];
            float4 xv = in4[c * BC4 + tid];
            acc.x += v * xv.x; acc.y += v * xv.y; acc.z += v * xv.z; acc.w += v * xv.w;
        }
        __syncthreads();
    }

    float4 res;
    if (has_sub) {
        float4 sv = ((const float4*)sub)[n * BC4 + tid];
        res.x = scale * acc.x - sv.x;
        res.y = scale * acc.y - sv.y;
        res.z = scale * acc.z - sv.z;
        res.w = scale * acc.w - sv.w;
    } else {
        res = acc;
    }
    ((float4*)out)[n * BC4 + tid] = res;
}

// ---------------- fused GEMM + bias + ReLU + maxpool ----------------
// out[b][g][o] = max_{p<4} relu(bias[o] + sum_{c,k} t_k[n][b*32+c] * W[c*5+k][o])
// grid: (N/16, B), block 256. Each block: one b, 16 nodes (4 pool groups).
// Thread: o = tid&63, group g = tid>>6 (4 nodes), 4 accumulators.

__global__ void gemm_pool_kernel(const float* __restrict__ tbase, const float* __restrict__ W,
                                 const float* __restrict__ bias, float* __restrict__ out) {
    __shared__ float lds_W[KDEG * CIN * COUT];  // [160][64] = 40 KB
    __shared__ float lds_t[KDEG * 16 * CIN];    // [5][16][32] = 10 KB

    int tid = threadIdx.x;
    int n0 = blockIdx.x * 16;
    int b  = blockIdx.y;

    // stage W: 2560 float4
    const float4* W4 = (const float4*)W;
    float4* lW4 = (float4*)lds_W;
#pragma unroll
    for (int q = 0; q < 10; q++) lW4[q * 256 + tid] = W4[q * 256 + tid];

    // stage t tile: 640 float4 ; layout lds_t[k][i][c]
    const float4* tb4 = (const float4*)tbase;
    float4* lT4 = (float4*)lds_t;
    for (int i4 = tid; i4 < 640; i4 += 256) {
        int k   = i4 >> 7;        // /128
        int rem = i4 & 127;
        int i   = rem >> 3;       // node within tile
        int c4  = rem & 7;
        lT4[i4] = tb4[(size_t)k * (TFLOATS / 4) + (n0 + i) * BC4 + b * 8 + c4];
    }
    __syncthreads();

    int o = tid & 63;
    int g = tid >> 6;     // pool group within tile (wave-uniform)
    float bi = bias[o];
    float a0 = bi, a1 = bi, a2 = bi, a3 = bi;

    const float4* lT4r = (const float4*)lds_t;
#pragma unroll
    for (int k = 0; k < KDEG; k++) {
#pragma unroll
        for (int c4 = 0; c4 < 8; c4++) {
            // broadcast reads (whole wave same address)
            float4 t0 = lT4r[k * 128 + (g * 4 + 0) * 8 + c4];
            float4 t1 = lT4r[k * 128 + (g * 4 + 1) * 8 + c4];
            float4 t2 = lT4r[k * 128 + (g * 4 + 2) * 8 + c4];
            float4 t3 = lT4r[k * 128 + (g * 4 + 3) * 8 + c4];
#pragma unroll
            for (int cc = 0; cc < 4; cc++) {
                int c = c4 * 4 + cc;
                float wv = lds_W[(c * KDEG + k) * COUT + o];
                float tv0 = (cc == 0) ? t0.x : (cc == 1) ? t0.y : (cc == 2) ? t0.z : t0.w;
                float tv1 = (cc == 0) ? t1.x : (cc == 1) ? t1.y : (cc == 2) ? t1.z : t1.w;
                float tv2 = (cc == 0) ? t2.x : (cc == 1) ? t2.y : (cc == 2) ? t2.z : t2.w;
                float tv3 = (cc == 0) ? t3.x : (cc == 1) ? t3.y : (cc == 2) ? t3.z : t3.w;
                a0 += tv0 * wv; a1 += tv1 * wv; a2 += tv2 * wv; a3 += tv3 * wv;
            }
        }
    }

    a0 = a0 > 0.f ? a0 : 0.f;
    a1 = a1 > 0.f ? a1 : 0.f;
    a2 = a2 > 0.f ? a2 : 0.f;
    a3 = a3 > 0.f ? a3 : 0.f;
    float mx = a0 > a1 ? a0 : a1;
    mx = mx > a2 ? mx : a2;
    mx = mx > a3 ? mx : a3;

    int group = (n0 >> 2) + g;                 // pool-group index in [0, N/4)
    out[((size_t)b * (NNODE / POOL) + group) * COUT + o] = mx;
}

// ---------------- launch ----------------

extern "C" void kernel_launch(void* const* d_in, const int* in_sizes, int n_in,
                              void* d_out, int out_size, void* d_ws, size_t ws_size,
                              hipStream_t stream) {
    const float* x    = (const float*)d_in[0];
    const float* eval = (const float*)d_in[1];
    const float* W    = (const float*)d_in[2];
    const float* bias = (const float*)d_in[3];
    const int*   erow = (const int*)d_in[4];
    const int*   ecol = (const int*)d_in[5];
    float* out = (float*)d_out;

    float* tb = (float*)d_ws;                          // 5 levels x 16 MB
    float* t0 = tb;
    float* t1 = tb + 1 * (size_t)TFLOATS;
    float* t2 = tb + 2 * (size_t)TFLOATS;
    float* t3 = tb + 3 * (size_t)TFLOATS;
    float* t4 = tb + 4 * (size_t)TFLOATS;

    int* csr = (int*)((char*)d_ws + 5 * (size_t)TFLOATS * sizeof(float));
    int* cnt       = csr;                  // 4096
    int* row_start = cnt + NNODE;          // 4097
    int* cursor    = row_start + NNODE + 1;// 4096
    int* perm      = cursor + NNODE;       // 65536

    // CSR build (d_ws is re-poisoned before every call -> rebuild each time)
    hipMemsetAsync(cnt, 0, NNODE * sizeof(int), stream);
    hist_kernel<<<NNZ_E / 256, 256, 0, stream>>>(erow, cnt);
    scan_kernel<<<1, 256, 0, stream>>>(cnt, row_start, cursor);
    scatter_kernel<<<NNZ_E / 256, 256, 0, stream>>>(erow, cursor, perm);

    // t0 = transpose(x)
    transpose_kernel<<<TFLOATS / 4 / 256, 256, 0, stream>>>(x, t0);

    // Chebyshev recursion
    spmm_cheb_kernel<<<NNODE, 256, 0, stream>>>(t0, nullptr, t1, 1.0f, 0,
                                                row_start, perm, eval, ecol);
    spmm_cheb_kernel<<<NNODE, 256, 0, stream>>>(t1, t0, t2, 2.0f, 1,
                                                row_start, perm, eval, ecol);
    spmm_cheb_kernel<<<NNODE, 256, 0, stream>>>(t2, t1, t3, 2.0f, 1,
                                                row_start, perm, eval, ecol);
    spmm_cheb_kernel<<<NNODE, 256, 0, stream>>>(t3, t2, t4, 2.0f, 1,
                                                row_start, perm, eval, ecol);

    // fused GEMM + bias + relu + maxpool
    gemm_pool_kernel<<<dim3(NNODE / 16, BATCH), 256, 0, stream>>>(tb, W, bias, out);
}

// Round 2
// 261.859 us; speedup vs baseline: 1.3026x; 1.3026x over previous
//
#include <hip/hip_runtime.h>
#include <hip/hip_bf16.h>

// Problem constants
#define BATCH 32
#define NNODE 4096
#define CIN 32
#define COUT 64
#define KDEG 5
#define POOL 4
#define NNZ_E 65536
#define BC (BATCH * CIN)        // 1024 floats per node-row
#define BC4 (BC / 4)            // 256 float4 per node-row
#define TFLOATS (NNODE * BC)    // 4,194,304 floats per Chebyshev level

typedef short s16x8 __attribute__((ext_vector_type(8)));
typedef float f32x4 __attribute__((ext_vector_type(4)));

// float -> bf16 bits, round-to-nearest-even (inputs are well-behaved, no NaN/inf)
__device__ __forceinline__ unsigned short f2bf(float f) {
    union { float f; unsigned int u; } v; v.f = f;
    unsigned int u = v.u;
    u += 0x7fffu + ((u >> 16) & 1u);
    return (unsigned short)(u >> 16);
}

// ---------------- CSR build ----------------

__global__ void hist_kernel(const int* __restrict__ erow, int* __restrict__ cnt) {
    int e = blockIdx.x * blockDim.x + threadIdx.x;
    if (e < NNZ_E) atomicAdd(&cnt[erow[e]], 1);
}

__global__ void scan_kernel(const int* __restrict__ cnt, int* __restrict__ row_start,
                            int* __restrict__ cursor) {
    __shared__ int sums[256];
    int tid = threadIdx.x;
    int local[16];
    int s = 0;
#pragma unroll
    for (int i = 0; i < 16; i++) { local[i] = cnt[tid * 16 + i]; s += local[i]; }
    sums[tid] = s;
    __syncthreads();
    for (int off = 1; off < 256; off <<= 1) {
        int v = 0;
        if (tid >= off) v = sums[tid - off];
        __syncthreads();
        if (tid >= off) sums[tid] += v;
        __syncthreads();
    }
    int base = sums[tid] - s;
    int run = base;
#pragma unroll
    for (int i = 0; i < 16; i++) {
        int r = tid * 16 + i;
        row_start[r] = run;
        cursor[r] = run;
        run += local[i];
    }
    if (tid == 255) row_start[NNODE] = sums[255];
}

__global__ void scatter_kernel(const int* __restrict__ erow, int* __restrict__ cursor,
                               int* __restrict__ perm) {
    int e = blockIdx.x * blockDim.x + threadIdx.x;
    if (e < NNZ_E) {
        int r = erow[e];
        int pos = atomicAdd(&cursor[r], 1);
        perm[pos] = e;
    }
}

// ---------------- pack W into bf16 B-fragment order: WB[k][o][c] ----------------
// B-frag for 16x16x32: lane holds B[kk=quad*8+j][nn=lane&15]; kk = c within level k.
// So lane (nn=o, quad) reads 8 contiguous c at WB[((k*64)+o)*32 + quad*8].

__global__ void pack_w_kernel(const float* __restrict__ W, unsigned short* __restrict__ WB) {
    int i = blockIdx.x * blockDim.x + threadIdx.x;   // [0, 5*64*32)
    if (i < KDEG * COUT * CIN) {
        int c = i & 31;
        int rest = i >> 5;
        int o = rest & 63;
        int k = rest >> 6;
        WB[i] = f2bf(W[(c * KDEG + k) * COUT + o]);
    }
}

// ---------------- transpose x [B][N][C] -> t0 [N][B*C] ----------------

__global__ void transpose_kernel(const float* __restrict__ x, float* __restrict__ t0) {
    int idx = blockIdx.x * blockDim.x + threadIdx.x;   // [0, TFLOATS/4)
    int n  = idx >> 8;
    int rem = idx & 255;
    int b  = rem >> 3;
    int c4 = rem & 7;
    const float4* x4 = (const float4*)x;
    float4 v = x4[(b * NNODE + n) * 8 + c4];
    ((float4*)t0)[idx] = v;
}

// ---------------- fused Chebyshev SpMM: out = scale * (L @ in) - sub ----------------

__global__ void spmm_cheb_kernel(const float* __restrict__ in, const float* __restrict__ sub,
                                 float* __restrict__ out, float scale, int has_sub,
                                 const int* __restrict__ row_start, const int* __restrict__ perm,
                                 const float* __restrict__ eval, const int* __restrict__ ecol) {
    __shared__ float sval[256];
    __shared__ int   scol[256];
    int n = blockIdx.x;
    int tid = threadIdx.x;
    int beg = row_start[n], end = row_start[n + 1];

    float4 acc = make_float4(0.f, 0.f, 0.f, 0.f);
    const float4* in4 = (const float4*)in;

    for (int base = beg; base < end; base += 256) {
        int m = end - base; if (m > 256) m = 256;
        if (tid < m) {
            int e = perm[base + tid];
            sval[tid] = eval[e];
            scol[tid] = ecol[e];
        }
        __syncthreads();
#pragma unroll 4
        for (int i = 0; i < m; i++) {
            float v = sval[i];
            int c = scol[i];
            float4 xv = in4[c * BC4 + tid];
            acc.x += v * xv.x; acc.y += v * xv.y; acc.z += v * xv.z; acc.w += v * xv.w;
        }
        __syncthreads();
    }

    float4 res;
    if (has_sub) {
        float4 sv = ((const float4*)sub)[n * BC4 + tid];
        res.x = scale * acc.x - sv.x;
        res.y = scale * acc.y - sv.y;
        res.z = scale * acc.z - sv.z;
        res.w = scale * acc.w - sv.w;
    } else {
        res = acc;
    }
    ((float4*)out)[n * BC4 + tid] = res;
}

// ---------------- MFMA GEMM + bias + ReLU + maxpool ----------------
// One wave = one (batch b, 16-node tile n0). Computes C[16 nodes][64 outs] via
// 5 K-steps x 4 o-tiles of mfma_f32_16x16x32_bf16, then pools in-lane:
// D row = quad*4+r  ->  lane's 4 rows are exactly pool group (n0/4 + quad).
// No LDS; A-frags loaded directly from global (8 contiguous floats -> bf16).

__global__ __launch_bounds__(256) void gemm_mfma_pool_kernel(
        const float* __restrict__ tbase, const unsigned short* __restrict__ WB,
        const float* __restrict__ bias, float* __restrict__ out) {
    int gtid = blockIdx.x * 256 + threadIdx.x;
    int lane = threadIdx.x & 63;
    int wid  = gtid >> 6;            // [0, 8192)
    int b    = wid >> 8;             // [0, 32)
    int n0   = (wid & 255) << 4;     // node tile base
    int m    = lane & 15;            // A row / B col / D col
    int q    = lane >> 4;            // quad

    f32x4 acc[4] = {{0.f,0.f,0.f,0.f},{0.f,0.f,0.f,0.f},
                    {0.f,0.f,0.f,0.f},{0.f,0.f,0.f,0.f}};

    const float* abase = tbase + (size_t)(n0 + m) * BC + b * CIN + q * 8;
    const unsigned short* wbase = WB + m * 32 + q * 8;

#pragma unroll
    for (int k = 0; k < KDEG; k++) {
        const float* ap = abase + (size_t)k * TFLOATS;
        float4 v0 = *(const float4*)ap;
        float4 v1 = *(const float4*)(ap + 4);
        s16x8 a;
        a[0] = (short)f2bf(v0.x); a[1] = (short)f2bf(v0.y);
        a[2] = (short)f2bf(v0.z); a[3] = (short)f2bf(v0.w);
        a[4] = (short)f2bf(v1.x); a[5] = (short)f2bf(v1.y);
        a[6] = (short)f2bf(v1.z); a[7] = (short)f2bf(v1.w);
#pragma unroll
        for (int ot = 0; ot < 4; ot++) {
            s16x8 bf = *(const s16x8*)(wbase + ((k * 64) + ot * 16) * 32);
            acc[ot] = __builtin_amdgcn_mfma_f32_16x16x32_bf16(a, bf, acc[ot], 0, 0, 0);
        }
    }

    size_t orow = ((size_t)b * (NNODE / POOL) + (n0 >> 2) + q) * COUT;
#pragma unroll
    for (int ot = 0; ot < 4; ot++) {
        float bi = bias[ot * 16 + m];
        float r0 = acc[ot][0] + bi; r0 = r0 > 0.f ? r0 : 0.f;
        float r1 = acc[ot][1] + bi; r1 = r1 > 0.f ? r1 : 0.f;
        float r2 = acc[ot][2] + bi; r2 = r2 > 0.f ? r2 : 0.f;
        float r3 = acc[ot][3] + bi; r3 = r3 > 0.f ? r3 : 0.f;
        float mx = r0 > r1 ? r0 : r1;
        mx = mx > r2 ? mx : r2;
        mx = mx > r3 ? mx : r3;
        out[orow + ot * 16 + m] = mx;
    }
}

// ---------------- launch ----------------

extern "C" void kernel_launch(void* const* d_in, const int* in_sizes, int n_in,
                              void* d_out, int out_size, void* d_ws, size_t ws_size,
                              hipStream_t stream) {
    const float* x    = (const float*)d_in[0];
    const float* eval = (const float*)d_in[1];
    const float* W    = (const float*)d_in[2];
    const float* bias = (const float*)d_in[3];
    const int*   erow = (const int*)d_in[4];
    const int*   ecol = (const int*)d_in[5];
    float* out = (float*)d_out;

    float* tb = (float*)d_ws;                          // 5 levels x 16 MB
    float* t0 = tb;
    float* t1 = tb + 1 * (size_t)TFLOATS;
    float* t2 = tb + 2 * (size_t)TFLOATS;
    float* t3 = tb + 3 * (size_t)TFLOATS;
    float* t4 = tb + 4 * (size_t)TFLOATS;

    int* csr = (int*)((char*)d_ws + 5 * (size_t)TFLOATS * sizeof(float));
    int* cnt       = csr;                  // 4096
    int* row_start = cnt + NNODE;          // 4097
    int* cursor    = row_start + NNODE + 1;// 4096
    int* perm      = cursor + NNODE;       // 65536
    // bf16 W pack, 64B-aligned, 20 KB
    size_t wb_off = (((size_t)(perm + NNZ_E - (int*)d_ws) * sizeof(int)) + 63) & ~(size_t)63;
    unsigned short* WB = (unsigned short*)((char*)d_ws + wb_off);

    // CSR build (d_ws is re-poisoned before every call -> rebuild each time)
    hipMemsetAsync(cnt, 0, NNODE * sizeof(int), stream);
    hist_kernel<<<NNZ_E / 256, 256, 0, stream>>>(erow, cnt);
    scan_kernel<<<1, 256, 0, stream>>>(cnt, row_start, cursor);
    scatter_kernel<<<NNZ_E / 256, 256, 0, stream>>>(erow, cursor, perm);

    // pack W into MFMA B-fragment order (bf16)
    pack_w_kernel<<<(KDEG * COUT * CIN + 255) / 256, 256, 0, stream>>>(W, WB);

    // t0 = transpose(x)
    transpose_kernel<<<TFLOATS / 4 / 256, 256, 0, stream>>>(x, t0);

    // Chebyshev recursion (fp32 throughout)
    spmm_cheb_kernel<<<NNODE, 256, 0, stream>>>(t0, nullptr, t1, 1.0f, 0,
                                                row_start, perm, eval, ecol);
    spmm_cheb_kernel<<<NNODE, 256, 0, stream>>>(t1, t0, t2, 2.0f, 1,
                                                row_start, perm, eval, ecol);
    spmm_cheb_kernel<<<NNODE, 256, 0, stream>>>(t2, t1, t3, 2.0f, 1,
                                                row_start, perm, eval, ecol);
    spmm_cheb_kernel<<<NNODE, 256, 0, stream>>>(t3, t2, t4, 2.0f, 1,
                                                row_start, perm, eval, ecol);

    // MFMA GEMM + bias + relu + maxpool (bf16 inputs, fp32 accumulate)
    gemm_mfma_pool_kernel<<<(BATCH * (NNODE / 16) * 64) / 256, 256, 0, stream>>>(
        tb, WB, bias, out);
}

// Round 3
// 258.481 us; speedup vs baseline: 1.3197x; 1.0131x over previous
//
#include <hip/hip_runtime.h>
#include <hip/hip_bf16.h>

// Problem constants
#define BATCH 32
#define NNODE 4096
#define CIN 32
#define COUT 64
#define KDEG 5
#define POOL 4
#define NNZ_E 65536
#define BC (BATCH * CIN)        // 1024 floats per node-row
#define BC4 (BC / 4)            // 256 float4 per node-row
#define TFLOATS (NNODE * BC)    // 4,194,304 floats per Chebyshev level

typedef short s16x8 __attribute__((ext_vector_type(8)));
typedef float f32x4 __attribute__((ext_vector_type(4)));

// float -> bf16 bits, round-to-nearest-even
__device__ __forceinline__ unsigned short f2bf(float f) {
    union { float f; unsigned int u; } v; v.f = f;
    unsigned int u = v.u;
    u += 0x7fffu + ((u >> 16) & 1u);
    return (unsigned short)(u >> 16);
}

// ---------------- prep: transpose x -> t0, edge histogram, pack W ----------------
// grid 4096 x 256. idx in [0, 1048576): transpose one float4.
// idx < 65536: histogram one edge. idx < 10240: pack one W element.

__global__ void prep_kernel(const float* __restrict__ x, float* __restrict__ t0,
                            const int* __restrict__ erow, int* __restrict__ cnt,
                            const float* __restrict__ W, unsigned short* __restrict__ WB) {
    int idx = blockIdx.x * 256 + threadIdx.x;
    // transpose [B][N][C] -> [N][B*C]
    int n   = idx >> 8;
    int rem = idx & 255;
    int b   = rem >> 3;
    int c4  = rem & 7;
    ((float4*)t0)[idx] = ((const float4*)x)[(b * NNODE + n) * 8 + c4];

    if (idx < NNZ_E) atomicAdd(&cnt[erow[idx]], 1);

    if (idx < KDEG * COUT * CIN) {
        int c = idx & 31;
        int rest = idx >> 5;
        int o = rest & 63;
        int k = rest >> 6;
        // WB[k][o][c] : B-fragment order for mfma_16x16x32 (lane nn=o, kk=c)
        WB[idx] = f2bf(W[(c * KDEG + k) * COUT + o]);
    }
}

// ---------------- scan: cnt -> row_start / cursor ----------------

__global__ void scan_kernel(const int* __restrict__ cnt, int* __restrict__ row_start,
                            int* __restrict__ cursor) {
    __shared__ int sums[256];
    int tid = threadIdx.x;
    int local[16];
    int s = 0;
#pragma unroll
    for (int i = 0; i < 16; i++) { local[i] = cnt[tid * 16 + i]; s += local[i]; }
    sums[tid] = s;
    __syncthreads();
    for (int off = 1; off < 256; off <<= 1) {
        int v = 0;
        if (tid >= off) v = sums[tid - off];
        __syncthreads();
        if (tid >= off) sums[tid] += v;
        __syncthreads();
    }
    int base = sums[tid] - s;
    int run = base;
#pragma unroll
    for (int i = 0; i < 16; i++) {
        int r = tid * 16 + i;
        row_start[r] = run;
        cursor[r] = run;
        run += local[i];
    }
    if (tid == 255) row_start[NNODE] = sums[255];
}

// ---------------- scatter edges row-sorted as (col, val_bits) pairs ----------------

__global__ void scatter_kernel(const int* __restrict__ erow, const int* __restrict__ ecol,
                               const float* __restrict__ eval, int* __restrict__ cursor,
                               int2* __restrict__ es) {
    int e = blockIdx.x * blockDim.x + threadIdx.x;
    if (e < NNZ_E) {
        int pos = atomicAdd(&cursor[erow[e]], 1);
        es[pos] = make_int2(ecol[e], __float_as_int(eval[e]));
    }
}

// ---------------- fused Chebyshev SpMM: out = scale * (L @ in) - sub ----------------
// One block per row n. No LDS, no barriers. Edge (col,val) reads are wave-uniform
// (scalar pipe); 8 independent float4 gathers in flight per lane per iteration.

__global__ __launch_bounds__(256) void spmm_cheb_kernel(
        const float* __restrict__ in, const float* __restrict__ sub,
        float* __restrict__ out, float scale, int has_sub,
        const int* __restrict__ row_start, const int2* __restrict__ es) {
    int n = blockIdx.x;
    int tid = threadIdx.x;
    int beg = row_start[n], end = row_start[n + 1];
    const float4* in4 = (const float4*)in;

    float4 a0 = make_float4(0.f, 0.f, 0.f, 0.f);
    float4 a1 = a0, a2 = a0, a3 = a0;

    for (int base = beg; base < end; base += 8) {
        float  vv[8];
        float4 xx[8];
#pragma unroll
        for (int j = 0; j < 8; j++) {
            int idx = base + j;
            int src = idx < end ? idx : beg;     // clamp: beg valid (loop entered)
            int2 e = es[src];                     // wave-uniform -> s_load
            vv[j] = idx < end ? __int_as_float(e.y) : 0.f;
            xx[j] = in4[(size_t)e.x * BC4 + tid]; // sgpr base + tid*16
        }
#pragma unroll
        for (int j = 0; j < 8; j++) {
            float4* ap = ((j & 3) == 0) ? &a0 : ((j & 3) == 1) ? &a1
                       : ((j & 3) == 2) ? &a2 : &a3;
            ap->x += vv[j] * xx[j].x;
            ap->y += vv[j] * xx[j].y;
            ap->z += vv[j] * xx[j].z;
            ap->w += vv[j] * xx[j].w;
        }
    }

    float4 acc;
    acc.x = (a0.x + a1.x) + (a2.x + a3.x);
    acc.y = (a0.y + a1.y) + (a2.y + a3.y);
    acc.z = (a0.z + a1.z) + (a2.z + a3.z);
    acc.w = (a0.w + a1.w) + (a2.w + a3.w);

    float4 res;
    if (has_sub) {
        float4 sv = ((const float4*)sub)[n * BC4 + tid];
        res.x = scale * acc.x - sv.x;
        res.y = scale * acc.y - sv.y;
        res.z = scale * acc.z - sv.z;
        res.w = scale * acc.w - sv.w;
    } else {
        res = acc;
    }
    ((float4*)out)[n * BC4 + tid] = res;
}

// ---------------- MFMA GEMM + bias + ReLU + maxpool ----------------
// One wave = one (batch b, 16-node tile). D row = quad*4+r -> lane's 4 acc rows
// are exactly one pool group; ReLU+maxpool collapse to in-lane max. No LDS.

__global__ __launch_bounds__(256) void gemm_mfma_pool_kernel(
        const float* __restrict__ tbase, const unsigned short* __restrict__ WB,
        const float* __restrict__ bias, float* __restrict__ out) {
    int gtid = blockIdx.x * 256 + threadIdx.x;
    int lane = threadIdx.x & 63;
    int wid  = gtid >> 6;            // [0, 8192)
    int b    = wid >> 8;             // [0, 32)
    int n0   = (wid & 255) << 4;     // node tile base
    int m    = lane & 15;
    int q    = lane >> 4;

    f32x4 acc[4] = {{0.f,0.f,0.f,0.f},{0.f,0.f,0.f,0.f},
                    {0.f,0.f,0.f,0.f},{0.f,0.f,0.f,0.f}};

    const float* abase = tbase + (size_t)(n0 + m) * BC + b * CIN + q * 8;
    const unsigned short* wbase = WB + m * 32 + q * 8;

#pragma unroll
    for (int k = 0; k < KDEG; k++) {
        const float* ap = abase + (size_t)k * TFLOATS;
        float4 v0 = *(const float4*)ap;
        float4 v1 = *(const float4*)(ap + 4);
        s16x8 a;
        a[0] = (short)f2bf(v0.x); a[1] = (short)f2bf(v0.y);
        a[2] = (short)f2bf(v0.z); a[3] = (short)f2bf(v0.w);
        a[4] = (short)f2bf(v1.x); a[5] = (short)f2bf(v1.y);
        a[6] = (short)f2bf(v1.z); a[7] = (short)f2bf(v1.w);
#pragma unroll
        for (int ot = 0; ot < 4; ot++) {
            s16x8 bf = *(const s16x8*)(wbase + ((k * 64) + ot * 16) * 32);
            acc[ot] = __builtin_amdgcn_mfma_f32_16x16x32_bf16(a, bf, acc[ot], 0, 0, 0);
        }
    }

    size_t orow = ((size_t)b * (NNODE / POOL) + (n0 >> 2) + q) * COUT;
#pragma unroll
    for (int ot = 0; ot < 4; ot++) {
        float bi = bias[ot * 16 + m];
        float r0 = acc[ot][0] + bi; r0 = r0 > 0.f ? r0 : 0.f;
        float r1 = acc[ot][1] + bi; r1 = r1 > 0.f ? r1 : 0.f;
        float r2 = acc[ot][2] + bi; r2 = r2 > 0.f ? r2 : 0.f;
        float r3 = acc[ot][3] + bi; r3 = r3 > 0.f ? r3 : 0.f;
        float mx = r0 > r1 ? r0 : r1;
        mx = mx > r2 ? mx : r2;
        mx = mx > r3 ? mx : r3;
        out[orow + ot * 16 + m] = mx;
    }
}

// ---------------- launch ----------------

extern "C" void kernel_launch(void* const* d_in, const int* in_sizes, int n_in,
                              void* d_out, int out_size, void* d_ws, size_t ws_size,
                              hipStream_t stream) {
    const float* x    = (const float*)d_in[0];
    const float* eval = (const float*)d_in[1];
    const float* W    = (const float*)d_in[2];
    const float* bias = (const float*)d_in[3];
    const int*   erow = (const int*)d_in[4];
    const int*   ecol = (const int*)d_in[5];
    float* out = (float*)d_out;

    char* base = (char*)d_ws;
    float* tb = (float*)base;                       // 5 levels x 16 MB
    float* t0 = tb;
    float* t1 = tb + 1 * (size_t)TFLOATS;
    float* t2 = tb + 2 * (size_t)TFLOATS;
    float* t3 = tb + 3 * (size_t)TFLOATS;
    float* t4 = tb + 4 * (size_t)TFLOATS;

    size_t off = 5 * (size_t)TFLOATS * sizeof(float);
    int2* es       = (int2*)(base + off);  off += (size_t)NNZ_E * sizeof(int2);
    int* cnt       = (int*)(base + off);   off += (size_t)NNODE * sizeof(int);
    int* row_start = (int*)(base + off);   off += (size_t)(NNODE + 1) * sizeof(int);
    int* cursor    = (int*)(base + off);   off += (size_t)NNODE * sizeof(int);
    off = (off + 63) & ~(size_t)63;
    unsigned short* WB = (unsigned short*)(base + off);

    // CSR build + transpose + W pack (d_ws re-poisoned every call -> rebuild)
    hipMemsetAsync(cnt, 0, NNODE * sizeof(int), stream);
    prep_kernel<<<TFLOATS / 4 / 256, 256, 0, stream>>>(x, t0, erow, cnt, W, WB);
    scan_kernel<<<1, 256, 0, stream>>>(cnt, row_start, cursor);
    scatter_kernel<<<NNZ_E / 256, 256, 0, stream>>>(erow, ecol, eval, cursor, es);

    // Chebyshev recursion (fp32 throughout)
    spmm_cheb_kernel<<<NNODE, 256, 0, stream>>>(t0, nullptr, t1, 1.0f, 0, row_start, es);
    spmm_cheb_kernel<<<NNODE, 256, 0, stream>>>(t1, t0, t2, 2.0f, 1, row_start, es);
    spmm_cheb_kernel<<<NNODE, 256, 0, stream>>>(t2, t1, t3, 2.0f, 1, row_start, es);
    spmm_cheb_kernel<<<NNODE, 256, 0, stream>>>(t3, t2, t4, 2.0f, 1, row_start, es);

    // MFMA GEMM + bias + relu + maxpool (bf16 inputs, fp32 accumulate)
    gemm_mfma_pool_kernel<<<(BATCH * (NNODE / 16) * 64) / 256, 256, 0, stream>>>(
        tb, WB, bias, out);
}

// Round 4
// 211.900 us; speedup vs baseline: 1.6098x; 1.2198x over previous
//
#include <hip/hip_runtime.h>
#include <hip/hip_bf16.h>

// Problem constants
#define BATCH 32
#define NNODE 4096
#define CIN 32
#define COUT 64
#define KDEG 5
#define POOL 4
#define NNZ_E 65536
#define BC (BATCH * CIN)        // 1024 floats per node-row
#define BC4 (BC / 4)            // 256 float4 per node-row
#define TFLOATS (NNODE * BC)    // 4,194,304 floats per Chebyshev level
#define NSLICE 8                // column slices (one per XCD)
#define SL4 (BC4 / NSLICE)      // 32 float4 per slice = 128 floats

typedef short s16x8 __attribute__((ext_vector_type(8)));
typedef float f32x4 __attribute__((ext_vector_type(4)));

// float -> bf16 bits, round-to-nearest-even
__device__ __forceinline__ unsigned short f2bf(float f) {
    union { float f; unsigned int u; } v; v.f = f;
    unsigned int u = v.u;
    u += 0x7fffu + ((u >> 16) & 1u);
    return (unsigned short)(u >> 16);
}

// ---------------- prep: transpose x -> t0, edge histogram, pack W ----------------

__global__ void prep_kernel(const float* __restrict__ x, float* __restrict__ t0,
                            const int* __restrict__ erow, int* __restrict__ cnt,
                            const float* __restrict__ W, unsigned short* __restrict__ WB) {
    int idx = blockIdx.x * 256 + threadIdx.x;
    // transpose [B][N][C] -> [N][B*C]
    int n   = idx >> 8;
    int rem = idx & 255;
    int b   = rem >> 3;
    int c4  = rem & 7;
    ((float4*)t0)[idx] = ((const float4*)x)[(b * NNODE + n) * 8 + c4];

    if (idx < NNZ_E) atomicAdd(&cnt[erow[idx]], 1);

    if (idx < KDEG * COUT * CIN) {
        int c = idx & 31;
        int rest = idx >> 5;
        int o = rest & 63;
        int k = rest >> 6;
        // WB[k][o][c] : B-fragment order for mfma_16x16x32 (lane nn=o, kk=c)
        WB[idx] = f2bf(W[(c * KDEG + k) * COUT + o]);
    }
}

// ---------------- scan: cnt -> row_start / cursor ----------------

__global__ void scan_kernel(const int* __restrict__ cnt, int* __restrict__ row_start,
                            int* __restrict__ cursor) {
    __shared__ int sums[256];
    int tid = threadIdx.x;
    int local[16];
    int s = 0;
#pragma unroll
    for (int i = 0; i < 16; i++) { local[i] = cnt[tid * 16 + i]; s += local[i]; }
    sums[tid] = s;
    __syncthreads();
    for (int off = 1; off < 256; off <<= 1) {
        int v = 0;
        if (tid >= off) v = sums[tid - off];
        __syncthreads();
        if (tid >= off) sums[tid] += v;
        __syncthreads();
    }
    int base = sums[tid] - s;
    int run = base;
#pragma unroll
    for (int i = 0; i < 16; i++) {
        int r = tid * 16 + i;
        row_start[r] = run;
        cursor[r] = run;
        run += local[i];
    }
    if (tid == 255) row_start[NNODE] = sums[255];
}

// ---------------- scatter edges row-sorted as (col, val_bits) pairs ----------------

__global__ void scatter_kernel(const int* __restrict__ erow, const int* __restrict__ ecol,
                               const float* __restrict__ eval, int* __restrict__ cursor,
                               int2* __restrict__ es) {
    int e = blockIdx.x * blockDim.x + threadIdx.x;
    if (e < NNZ_E) {
        int pos = atomicAdd(&cursor[erow[e]], 1);
        es[pos] = make_int2(ecol[e], __float_as_int(eval[e]));
    }
}

// ---------------- column-sliced Chebyshev SpMM: out = scale*(L@in) - sub ----------
// Slice s = 128 cols (2 MB working set) pinned to XCD s via blockIdx&7 swizzle.
// One wave per (row, slice): lanes = 2 edge-groups x 32 float4-cols; 4-deep
// unroll -> 8 gathers in flight; shfl_xor(32) final reduce. Streaming sub/out
// use nontemporal ops so the L2 keeps the gather working set.

__global__ __launch_bounds__(256) void spmm_cheb_slice_kernel(
        const float* __restrict__ in, const float* __restrict__ sub,
        float* __restrict__ out, float scale, int has_sub,
        const int* __restrict__ row_start, const int2* __restrict__ es) {
    int bx    = blockIdx.x;            // [0, 8192)
    int slice = bx & 7;                // XCD-matched column slice
    int rg    = bx >> 3;               // [0, 1024) row group of 4
    int wave  = threadIdx.x >> 6;      // 0..3
    int lane  = threadIdx.x & 63;
    int r     = rg * 4 + wave;         // node row
    int ep    = lane >> 5;             // edge-parallel group 0..1
    int c     = lane & 31;             // float4 col within slice
    int cb    = slice * SL4 + c;       // absolute float4 col

    const float4* in4 = (const float4*)in;
    int beg = row_start[r], end = row_start[r + 1];

    float4 a0 = make_float4(0.f, 0.f, 0.f, 0.f);
    float4 a1 = a0, a2 = a0, a3 = a0;

    for (int base = beg + ep; base < end; base += 8) {
        float  vv[4];
        float4 xx[4];
#pragma unroll
        for (int j = 0; j < 4; j++) {
            int idx = base + 2 * j;
            int src = idx < end ? idx : beg;      // beg valid: loop was entered
            int2 e = es[src];
            vv[j] = idx < end ? __int_as_float(e.y) : 0.f;
            xx[j] = in4[(size_t)e.x * BC4 + cb];  // L2-hot gather
        }
        a0.x += vv[0] * xx[0].x; a0.y += vv[0] * xx[0].y;
        a0.z += vv[0] * xx[0].z; a0.w += vv[0] * xx[0].w;
        a1.x += vv[1] * xx[1].x; a1.y += vv[1] * xx[1].y;
        a1.z += vv[1] * xx[1].z; a1.w += vv[1] * xx[1].w;
        a2.x += vv[2] * xx[2].x; a2.y += vv[2] * xx[2].y;
        a2.z += vv[2] * xx[2].z; a2.w += vv[2] * xx[2].w;
        a3.x += vv[3] * xx[3].x; a3.y += vv[3] * xx[3].y;
        a3.z += vv[3] * xx[3].z; a3.w += vv[3] * xx[3].w;
    }

    float4 acc;
    acc.x = (a0.x + a1.x) + (a2.x + a3.x);
    acc.y = (a0.y + a1.y) + (a2.y + a3.y);
    acc.z = (a0.z + a1.z) + (a2.z + a3.z);
    acc.w = (a0.w + a1.w) + (a2.w + a3.w);

    // combine the two edge-parallel halves
    acc.x += __shfl_xor(acc.x, 32);
    acc.y += __shfl_xor(acc.y, 32);
    acc.z += __shfl_xor(acc.z, 32);
    acc.w += __shfl_xor(acc.w, 32);

    if (ep == 0) {
        size_t oi = (size_t)r * BC4 + cb;
        f32x4 res;
        if (has_sub) {
            f32x4 sv = __builtin_nontemporal_load((const f32x4*)sub + oi);
            res[0] = scale * acc.x - sv[0];
            res[1] = scale * acc.y - sv[1];
            res[2] = scale * acc.z - sv[2];
            res[3] = scale * acc.w - sv[3];
        } else {
            res[0] = acc.x; res[1] = acc.y; res[2] = acc.z; res[3] = acc.w;
        }
        __builtin_nontemporal_store(res, (f32x4*)out + oi);
    }
}

// ---------------- MFMA GEMM + bias + ReLU + maxpool ----------------
// One wave = one (batch b, 16-node tile). D row = quad*4+r -> lane's 4 acc rows
// are exactly one pool group; ReLU+maxpool collapse to in-lane max. No LDS.

__global__ __launch_bounds__(256) void gemm_mfma_pool_kernel(
        const float* __restrict__ tbase, const unsigned short* __restrict__ WB,
        const float* __restrict__ bias, float* __restrict__ out) {
    int gtid = blockIdx.x * 256 + threadIdx.x;
    int lane = threadIdx.x & 63;
    int wid  = gtid >> 6;            // [0, 8192)
    int b    = wid >> 8;             // [0, 32)
    int n0   = (wid & 255) << 4;     // node tile base
    int m    = lane & 15;
    int q    = lane >> 4;

    f32x4 acc[4] = {{0.f,0.f,0.f,0.f},{0.f,0.f,0.f,0.f},
                    {0.f,0.f,0.f,0.f},{0.f,0.f,0.f,0.f}};

    const float* abase = tbase + (size_t)(n0 + m) * BC + b * CIN + q * 8;
    const unsigned short* wbase = WB + m * 32 + q * 8;

#pragma unroll
    for (int k = 0; k < KDEG; k++) {
        const float* ap = abase + (size_t)k * TFLOATS;
        float4 v0 = *(const float4*)ap;
        float4 v1 = *(const float4*)(ap + 4);
        s16x8 a;
        a[0] = (short)f2bf(v0.x); a[1] = (short)f2bf(v0.y);
        a[2] = (short)f2bf(v0.z); a[3] = (short)f2bf(v0.w);
        a[4] = (short)f2bf(v1.x); a[5] = (short)f2bf(v1.y);
        a[6] = (short)f2bf(v1.z); a[7] = (short)f2bf(v1.w);
#pragma unroll
        for (int ot = 0; ot < 4; ot++) {
            s16x8 bf = *(const s16x8*)(wbase + ((k * 64) + ot * 16) * 32);
            acc[ot] = __builtin_amdgcn_mfma_f32_16x16x32_bf16(a, bf, acc[ot], 0, 0, 0);
        }
    }

    size_t orow = ((size_t)b * (NNODE / POOL) + (n0 >> 2) + q) * COUT;
#pragma unroll
    for (int ot = 0; ot < 4; ot++) {
        float bi = bias[ot * 16 + m];
        float r0 = acc[ot][0] + bi; r0 = r0 > 0.f ? r0 : 0.f;
        float r1 = acc[ot][1] + bi; r1 = r1 > 0.f ? r1 : 0.f;
        float r2 = acc[ot][2] + bi; r2 = r2 > 0.f ? r2 : 0.f;
        float r3 = acc[ot][3] + bi; r3 = r3 > 0.f ? r3 : 0.f;
        float mx = r0 > r1 ? r0 : r1;
        mx = mx > r2 ? mx : r2;
        mx = mx > r3 ? mx : r3;
        out[orow + ot * 16 + m] = mx;
    }
}

// ---------------- launch ----------------

extern "C" void kernel_launch(void* const* d_in, const int* in_sizes, int n_in,
                              void* d_out, int out_size, void* d_ws, size_t ws_size,
                              hipStream_t stream) {
    const float* x    = (const float*)d_in[0];
    const float* eval = (const float*)d_in[1];
    const float* W    = (const float*)d_in[2];
    const float* bias = (const float*)d_in[3];
    const int*   erow = (const int*)d_in[4];
    const int*   ecol = (const int*)d_in[5];
    float* out = (float*)d_out;

    char* base = (char*)d_ws;
    float* tb = (float*)base;                       // 5 levels x 16 MB
    float* t0 = tb;
    float* t1 = tb + 1 * (size_t)TFLOATS;
    float* t2 = tb + 2 * (size_t)TFLOATS;
    float* t3 = tb + 3 * (size_t)TFLOATS;
    float* t4 = tb + 4 * (size_t)TFLOATS;

    size_t off = 5 * (size_t)TFLOATS * sizeof(float);
    int2* es       = (int2*)(base + off);  off += (size_t)NNZ_E * sizeof(int2);
    int* cnt       = (int*)(base + off);   off += (size_t)NNODE * sizeof(int);
    int* row_start = (int*)(base + off);   off += (size_t)(NNODE + 1) * sizeof(int);
    int* cursor    = (int*)(base + off);   off += (size_t)NNODE * sizeof(int);
    off = (off + 63) & ~(size_t)63;
    unsigned short* WB = (unsigned short*)(base + off);

    // CSR build + transpose + W pack (d_ws re-poisoned every call -> rebuild)
    hipMemsetAsync(cnt, 0, NNODE * sizeof(int), stream);
    prep_kernel<<<TFLOATS / 4 / 256, 256, 0, stream>>>(x, t0, erow, cnt, W, WB);
    scan_kernel<<<1, 256, 0, stream>>>(cnt, row_start, cursor);
    scatter_kernel<<<NNZ_E / 256, 256, 0, stream>>>(erow, ecol, eval, cursor, es);

    // Chebyshev recursion, column-sliced for L2 residency (fp32 throughout)
    spmm_cheb_slice_kernel<<<NNODE * 2, 256, 0, stream>>>(t0, nullptr, t1, 1.0f, 0,
                                                          row_start, es);
    spmm_cheb_slice_kernel<<<NNODE * 2, 256, 0, stream>>>(t1, t0, t2, 2.0f, 1,
                                                          row_start, es);
    spmm_cheb_slice_kernel<<<NNODE * 2, 256, 0, stream>>>(t2, t1, t3, 2.0f, 1,
                                                          row_start, es);
    spmm_cheb_slice_kernel<<<NNODE * 2, 256, 0, stream>>>(t3, t2, t4, 2.0f, 1,
                                                          row_start, es);

    // MFMA GEMM + bias + relu + maxpool (bf16 inputs, fp32 accumulate)
    gemm_mfma_pool_kernel<<<(BATCH * (NNODE / 16) * 64) / 256, 256, 0, stream>>>(
        tb, WB, bias, out);
}

// Round 5
// 195.244 us; speedup vs baseline: 1.7471x; 1.0853x over previous
//
#include <hip/hip_runtime.h>
#include <hip/hip_bf16.h>

// Problem constants
#define BATCH 32
#define NNODE 4096
#define CIN 32
#define COUT 64
#define KDEG 5
#define POOL 4
#define NNZ_E 65536
#define BC (BATCH * CIN)        // 1024 elems per node-row
#define TBF ((size_t)NNODE * BC) // elems per Chebyshev level (bf16 storage)
#define NSLICE 8                // column slices (one per XCD)

typedef short s16x8 __attribute__((ext_vector_type(8)));
typedef float f32x4 __attribute__((ext_vector_type(4)));
typedef unsigned long long u64;

// float -> bf16 bits, round-to-nearest-even
__device__ __forceinline__ unsigned short f2bf(float f) {
    union { float f; unsigned int u; } v; v.f = f;
    unsigned int u = v.u;
    u += 0x7fffu + ((u >> 16) & 1u);
    return (unsigned short)(u >> 16);
}
__device__ __forceinline__ float bf2f(unsigned short b) {
    union { float f; unsigned int u; } v; v.u = ((unsigned int)b) << 16;
    return v.f;
}
__device__ __forceinline__ u64 pack4(float a, float b, float c, float d) {
    return (u64)f2bf(a) | ((u64)f2bf(b) << 16) | ((u64)f2bf(c) << 32) | ((u64)f2bf(d) << 48);
}

// ---------------- prep: transpose x -> t0 (bf16), edge histogram, pack W --------

__global__ void prep_kernel(const float* __restrict__ x, unsigned short* __restrict__ t0,
                            const int* __restrict__ erow, int* __restrict__ cnt,
                            const float* __restrict__ W, unsigned short* __restrict__ WB) {
    int idx = blockIdx.x * 256 + threadIdx.x;   // [0, 1048576)
    // transpose [B][N][C] -> [N][B*C], 4 elems per thread
    int n   = idx >> 8;
    int rem = idx & 255;
    int b   = rem >> 3;
    int c4  = rem & 7;
    float4 v = ((const float4*)x)[(b * NNODE + n) * 8 + c4];
    ((u64*)t0)[idx] = pack4(v.x, v.y, v.z, v.w);   // elem offset = 4*idx = n*1024+b*32+c4*4

    if (idx < NNZ_E) atomicAdd(&cnt[erow[idx]], 1);

    if (idx < KDEG * COUT * CIN) {
        int c = idx & 31;
        int rest = idx >> 5;
        int o = rest & 63;
        int k = rest >> 6;
        // WB[k][o][c] : B-fragment order for mfma_16x16x32 (lane nn=o, kk=c)
        WB[idx] = f2bf(W[(c * KDEG + k) * COUT + o]);
    }
}

// ---------------- scan: cnt -> row_start / cursor ----------------

__global__ void scan_kernel(const int* __restrict__ cnt, int* __restrict__ row_start,
                            int* __restrict__ cursor) {
    __shared__ int sums[256];
    int tid = threadIdx.x;
    int local[16];
    int s = 0;
#pragma unroll
    for (int i = 0; i < 16; i++) { local[i] = cnt[tid * 16 + i]; s += local[i]; }
    sums[tid] = s;
    __syncthreads();
    for (int off = 1; off < 256; off <<= 1) {
        int v = 0;
        if (tid >= off) v = sums[tid - off];
        __syncthreads();
        if (tid >= off) sums[tid] += v;
        __syncthreads();
    }
    int base = sums[tid] - s;
    int run = base;
#pragma unroll
    for (int i = 0; i < 16; i++) {
        int r = tid * 16 + i;
        row_start[r] = run;
        cursor[r] = run;
        run += local[i];
    }
    if (tid == 255) row_start[NNODE] = sums[255];
}

// ---------------- scatter edges row-sorted as (col, val_bits) pairs ----------------

__global__ void scatter_kernel(const int* __restrict__ erow, const int* __restrict__ ecol,
                               const float* __restrict__ eval, int* __restrict__ cursor,
                               int2* __restrict__ es) {
    int e = blockIdx.x * blockDim.x + threadIdx.x;
    if (e < NNZ_E) {
        int pos = atomicAdd(&cursor[erow[e]], 1);
        es[pos] = make_int2(ecol[e], __float_as_int(eval[e]));
    }
}

// ---------------- column-sliced bf16 Chebyshev SpMM: out = scale*(L@in) - sub ----
// Slice = 128 cols = 256 B/row -> 1 MB working set, pinned to XCD (blockIdx&7).
// out-store goes THROUGH L2 (no nt): XCD s's L2 retains the slice it writes,
// which is exactly what it gathers next level. sub-read stays nontemporal.
// One wave per (row, slice): 2 edge groups x 32 lanes x 4 bf16; fp32 accumulate.

__global__ __launch_bounds__(256) void spmm_cheb_slice_kernel(
        const unsigned short* __restrict__ in, const unsigned short* __restrict__ sub,
        unsigned short* __restrict__ out, float scale, int has_sub,
        const int* __restrict__ row_start, const int2* __restrict__ es) {
    int bx    = blockIdx.x;            // [0, 8192)
    int slice = bx & 7;                // XCD-matched column slice
    int rg    = bx >> 3;               // [0, 1024) row group of 4
    int wave  = threadIdx.x >> 6;      // 0..3
    int lane  = threadIdx.x & 63;
    int r     = rg * 4 + wave;         // node row
    int ep    = lane >> 5;             // edge-parallel group 0..1
    int c     = lane & 31;             // u64 (4-elem) col within slice
    int sc    = slice * 32 + c;        // absolute u64 col in row (256 per row)

    const u64* in8 = (const u64*)in;
    int beg = row_start[r], end = row_start[r + 1];

    float4 a0 = make_float4(0.f, 0.f, 0.f, 0.f);
    float4 a1 = a0, a2 = a0, a3 = a0;

    for (int base = beg + ep; base < end; base += 8) {
        float vv[4];
        u64   xx[4];
#pragma unroll
        for (int j = 0; j < 4; j++) {
            int idx = base + 2 * j;
            int src = idx < end ? idx : beg;      // beg valid: loop was entered
            int2 e = es[src];
            vv[j] = idx < end ? __int_as_float(e.y) : 0.f;
            xx[j] = in8[(size_t)e.x * 256 + sc];  // 8B gather, L2-hot
        }
        a0.x += vv[0] * bf2f((unsigned short)xx[0]);
        a0.y += vv[0] * bf2f((unsigned short)(xx[0] >> 16));
        a0.z += vv[0] * bf2f((unsigned short)(xx[0] >> 32));
        a0.w += vv[0] * bf2f((unsigned short)(xx[0] >> 48));
        a1.x += vv[1] * bf2f((unsigned short)xx[1]);
        a1.y += vv[1] * bf2f((unsigned short)(xx[1] >> 16));
        a1.z += vv[1] * bf2f((unsigned short)(xx[1] >> 32));
        a1.w += vv[1] * bf2f((unsigned short)(xx[1] >> 48));
        a2.x += vv[2] * bf2f((unsigned short)xx[2]);
        a2.y += vv[2] * bf2f((unsigned short)(xx[2] >> 16));
        a2.z += vv[2] * bf2f((unsigned short)(xx[2] >> 32));
        a2.w += vv[2] * bf2f((unsigned short)(xx[2] >> 48));
        a3.x += vv[3] * bf2f((unsigned short)xx[3]);
        a3.y += vv[3] * bf2f((unsigned short)(xx[3] >> 16));
        a3.z += vv[3] * bf2f((unsigned short)(xx[3] >> 32));
        a3.w += vv[3] * bf2f((unsigned short)(xx[3] >> 48));
    }

    float4 acc;
    acc.x = (a0.x + a1.x) + (a2.x + a3.x);
    acc.y = (a0.y + a1.y) + (a2.y + a3.y);
    acc.z = (a0.z + a1.z) + (a2.z + a3.z);
    acc.w = (a0.w + a1.w) + (a2.w + a3.w);

    // combine the two edge-parallel halves
    acc.x += __shfl_xor(acc.x, 32);
    acc.y += __shfl_xor(acc.y, 32);
    acc.z += __shfl_xor(acc.z, 32);
    acc.w += __shfl_xor(acc.w, 32);

    if (ep == 0) {
        size_t oi = (size_t)r * 256 + sc;
        float r0, r1, r2, r3;
        if (has_sub) {
            u64 sv = __builtin_nontemporal_load((const u64*)sub + oi);
            r0 = scale * acc.x - bf2f((unsigned short)sv);
            r1 = scale * acc.y - bf2f((unsigned short)(sv >> 16));
            r2 = scale * acc.z - bf2f((unsigned short)(sv >> 32));
            r3 = scale * acc.w - bf2f((unsigned short)(sv >> 48));
        } else {
            r0 = acc.x; r1 = acc.y; r2 = acc.z; r3 = acc.w;
        }
        ((u64*)out)[oi] = pack4(r0, r1, r2, r3);   // normal store: keep slice in L2
    }
}

// ---------------- MFMA GEMM + bias + ReLU + maxpool ----------------
// One wave = one (batch b, 16-node tile). D row = quad*4+r -> lane's 4 acc rows
// are exactly one pool group; ReLU+maxpool collapse to in-lane max. No LDS.
// A-frags: single 16B bf16 load, no conversion.

__global__ __launch_bounds__(256) void gemm_mfma_pool_kernel(
        const unsigned short* __restrict__ tbase, const unsigned short* __restrict__ WB,
        const float* __restrict__ bias, float* __restrict__ out) {
    int gtid = blockIdx.x * 256 + threadIdx.x;
    int lane = threadIdx.x & 63;
    int wid  = gtid >> 6;            // [0, 8192)
    int b    = wid >> 8;             // [0, 32)
    int n0   = (wid & 255) << 4;     // node tile base
    int m    = lane & 15;
    int q    = lane >> 4;

    f32x4 acc[4] = {{0.f,0.f,0.f,0.f},{0.f,0.f,0.f,0.f},
                    {0.f,0.f,0.f,0.f},{0.f,0.f,0.f,0.f}};

    const unsigned short* abase = tbase + (size_t)(n0 + m) * BC + b * CIN + q * 8;
    const unsigned short* wbase = WB + m * 32 + q * 8;

#pragma unroll
    for (int k = 0; k < KDEG; k++) {
        s16x8 a = *(const s16x8*)(abase + (size_t)k * TBF);
#pragma unroll
        for (int ot = 0; ot < 4; ot++) {
            s16x8 bf = *(const s16x8*)(wbase + ((k * 64) + ot * 16) * 32);
            acc[ot] = __builtin_amdgcn_mfma_f32_16x16x32_bf16(a, bf, acc[ot], 0, 0, 0);
        }
    }

    size_t orow = ((size_t)b * (NNODE / POOL) + (n0 >> 2) + q) * COUT;
#pragma unroll
    for (int ot = 0; ot < 4; ot++) {
        float bi = bias[ot * 16 + m];
        float r0 = acc[ot][0] + bi; r0 = r0 > 0.f ? r0 : 0.f;
        float r1 = acc[ot][1] + bi; r1 = r1 > 0.f ? r1 : 0.f;
        float r2 = acc[ot][2] + bi; r2 = r2 > 0.f ? r2 : 0.f;
        float r3 = acc[ot][3] + bi; r3 = r3 > 0.f ? r3 : 0.f;
        float mx = r0 > r1 ? r0 : r1;
        mx = mx > r2 ? mx : r2;
        mx = mx > r3 ? mx : r3;
        out[orow + ot * 16 + m] = mx;
    }
}

// ---------------- launch ----------------

extern "C" void kernel_launch(void* const* d_in, const int* in_sizes, int n_in,
                              void* d_out, int out_size, void* d_ws, size_t ws_size,
                              hipStream_t stream) {
    const float* x    = (const float*)d_in[0];
    const float* eval = (const float*)d_in[1];
    const float* W    = (const float*)d_in[2];
    const float* bias = (const float*)d_in[3];
    const int*   erow = (const int*)d_in[4];
    const int*   ecol = (const int*)d_in[5];
    float* out = (float*)d_out;

    char* base = (char*)d_ws;
    unsigned short* tb = (unsigned short*)base;     // 5 levels x 8 MB (bf16)
    unsigned short* t0 = tb;
    unsigned short* t1 = tb + 1 * TBF;
    unsigned short* t2 = tb + 2 * TBF;
    unsigned short* t3 = tb + 3 * TBF;
    unsigned short* t4 = tb + 4 * TBF;

    size_t off = 5 * TBF * sizeof(unsigned short);
    int2* es       = (int2*)(base + off);  off += (size_t)NNZ_E * sizeof(int2);
    int* cnt       = (int*)(base + off);   off += (size_t)NNODE * sizeof(int);
    int* row_start = (int*)(base + off);   off += (size_t)(NNODE + 1) * sizeof(int);
    int* cursor    = (int*)(base + off);   off += (size_t)NNODE * sizeof(int);
    off = (off + 63) & ~(size_t)63;
    unsigned short* WB = (unsigned short*)(base + off);

    // CSR build + transpose + W pack (d_ws re-poisoned every call -> rebuild)
    hipMemsetAsync(cnt, 0, NNODE * sizeof(int), stream);
    prep_kernel<<<TBF / 4 / 256, 256, 0, stream>>>(x, t0, erow, cnt, W, WB);
    scan_kernel<<<1, 256, 0, stream>>>(cnt, row_start, cursor);
    scatter_kernel<<<NNZ_E / 256, 256, 0, stream>>>(erow, ecol, eval, cursor, es);

    // Chebyshev recursion, column-sliced, bf16 storage / fp32 accumulate
    spmm_cheb_slice_kernel<<<NNODE * 2, 256, 0, stream>>>(t0, nullptr, t1, 1.0f, 0,
                                                          row_start, es);
    spmm_cheb_slice_kernel<<<NNODE * 2, 256, 0, stream>>>(t1, t0, t2, 2.0f, 1,
                                                          row_start, es);
    spmm_cheb_slice_kernel<<<NNODE * 2, 256, 0, stream>>>(t2, t1, t3, 2.0f, 1,
                                                          row_start, es);
    spmm_cheb_slice_kernel<<<NNODE * 2, 256, 0, stream>>>(t3, t2, t4, 2.0f, 1,
                                                          row_start, es);

    // MFMA GEMM + bias + relu + maxpool (bf16 inputs, fp32 accumulate)
    gemm_mfma_pool_kernel<<<(BATCH * (NNODE / 16) * 64) / 256, 256, 0, stream>>>(
        tb, WB, bias, out);
}